// Round 22
// baseline (360.987 us; speedup 1.0000x reference)
//
#include <hip/hip_runtime.h>
#include <hip/hip_cooperative_groups.h>
#include <stdint.h>
#include <stddef.h>

namespace cg = cooperative_groups;

#define BB 64
#define DIN 1024
#define DD 768
#define CC 1000
#define EPSA 0.1f
#define NSIM 3
#define NEGINF -3.402823466e38f

typedef short  s16x8 __attribute__((ext_vector_type(8)));
typedef float  f32x4 __attribute__((ext_vector_type(4)));

static __device__ __forceinline__ unsigned short f2bf_rne(float x) {
  unsigned u = __float_as_uint(x);
  return (unsigned short)((u + 0x7FFFu + ((u >> 16) & 1u)) >> 16);
}
static __device__ __forceinline__ float bf2f(unsigned short h) {
  return __uint_as_float(((unsigned)h) << 16);
}

// ---------------------------------------------------------------- prep: pack {W_fc,anchors,W_emb,x} to bf16 frags + An2
// + tail block: zero amaxP and Pe k-pad slots (every replay)
__global__ __launch_bounds__(256) void prep_kernel(const float* __restrict__ W_fc,
                                                   const float* __restrict__ anchors,
                                                   const float* __restrict__ W_emb,
                                                   const float* __restrict__ x,
                                                   short* __restrict__ Bp, short* __restrict__ Ap,
                                                   short* __restrict__ Ip, short* __restrict__ Xp,
                                                   float* __restrict__ An2,
                                                   unsigned long long* __restrict__ amaxP,
                                                   short* __restrict__ Pe) {
  const int blk = blockIdx.x, tid = threadIdx.x;
  if (blk < 1184) {
    const float* src; short* dst; int KS, nrow, gid;
    if (blk < 384)       { src = W_fc;    dst = Bp; KS = 24; nrow = CC;  gid = blk * 256 + tid; }
    else if (blk < 768)  { src = anchors; dst = Ap; KS = 24; nrow = CC;  gid = (blk - 384) * 256 + tid; }
    else if (blk < 1152) { src = W_emb;   dst = Ip; KS = 32; nrow = DD;  gid = (blk - 768) * 256 + tid; }
    else                 { src = x;       dst = Xp; KS = 32; nrow = BB;  gid = (blk - 1152) * 256 + tid; }
    int lane = gid & 63;
    int ks   = (gid >> 6) % KS;
    int nt   = gid / (64 * KS);
    int row  = nt * 16 + (lane & 15);
    int k0   = ks * 32 + (lane >> 4) * 8;
    int stride = KS * 32;
    s16x8 v;
    #pragma unroll
    for (int r = 0; r < 8; ++r) {
      float w = (row < nrow) ? src[(size_t)row * stride + k0 + r] : 0.0f;
      v[r] = (short)f2bf_rne(w);
    }
    ((s16x8*)dst)[gid] = v;
  } else if (blk < 1434) {
    int w = tid >> 6, lane = tid & 63;
    int j = (blk - 1184) * 4 + w;          // < 1000
    const float4* ar = (const float4*)(anchors + (size_t)j * DD);
    float an = 0.f;
    for (int k4 = lane; k4 < DD / 4; k4 += 64) {
      float4 a = ar[k4];
      an += a.x*a.x + a.y*a.y + a.z*a.z + a.w*a.w;
    }
    #pragma unroll
    for (int o = 1; o < 64; o <<= 1) an += __shfl_xor(an, o);
    if (lane == 0) An2[j] = an;
  } else {
    if (tid < 64) amaxP[tid] = 0ull;
    for (int idx = tid; idx < 1536; idx += 256) {   // Pe pads: c = 1000..1023 for each b
      int b = idx / 24, cp = 1000 + idx % 24;
      int mt = b >> 4, blo = b & 15;
      size_t fi = ((size_t)(mt * 32 + (cp >> 5)) * 64 + ((cp >> 3) & 3) * 16 + blo) * 8 + (cp & 7);
      Pe[fi] = 0;
    }
  }
}

// ---------------------------------------------------------------- mega: embV -> logitsAE -> u -> stats -> scan -> counts
// 512 blocks x 256 threads, cooperative; each phase keeps its proven grid shape.
__global__ __launch_bounds__(256, 2) void mega_kernel(
    const short* __restrict__ Bp, const short* __restrict__ Ip, const short* __restrict__ Xp,
    const float* __restrict__ b_emb, unsigned short* __restrict__ Vb, short* __restrict__ Vp,
    float* __restrict__ emb, short* __restrict__ Ep, const short* __restrict__ Ap,
    const float* __restrict__ b_fc, float* __restrict__ logits, float* __restrict__ AE,
    short* __restrict__ Pe, unsigned long long* __restrict__ amaxP, float* __restrict__ ue,
    const float* __restrict__ An2, float* __restrict__ stats,
    unsigned long long* __restrict__ part, float* __restrict__ out) {
  cg::grid_group grid = cg::this_grid();
  const int blk = blockIdx.x;
  const int tid = threadIdx.x, w = tid >> 6, lane = tid & 63;
  __shared__ __attribute__((aligned(16))) char smem[9472];

  // ================= phase E: embV (blocks 0..267) =================
  if (blk < 268) {
    short* lsh = (short*)smem;
    if (blk < 256) {
      const int bx = blk & 15, cb = blk >> 4;
      const int rnt = bx * 4 + w;
      const s16x8* BH = (const s16x8*)Bp;
      f32x4 acc[4] = {};
      for (int ks = 0; ks < 24; ++ks) {
        s16x8 a = BH[(rnt * 24 + ks) * 64 + lane];
        #pragma unroll
        for (int nf = 0; nf < 4; ++nf)
          acc[nf] = __builtin_amdgcn_mfma_f32_16x16x32_bf16(a, BH[((cb * 4 + nf) * 24 + ks) * 64 + lane], acc[nf], 0, 0, 0);
      }
      const int rl0 = (lane >> 4) * 4;             // C/D: row=(lane>>4)*4+reg, col=lane&15 [m89]
      const int r0 = rnt * 16 + rl0;
      const int c0 = cb * 64 + (lane & 15);
      #pragma unroll
      for (int nf = 0; nf < 4; ++nf)
        #pragma unroll
        for (int rr = 0; rr < 4; ++rr) {
          unsigned short h = f2bf_rne(acc[nf][rr]);
          Vb[(size_t)(r0 + rr) * 1024 + c0 + nf * 16] = h;
          lsh[w * 1152 + (rl0 + rr) * 72 + (lane & 15) + nf * 16] = (short)h;
        }
      __syncthreads();
      #pragma unroll
      for (int ksh = 0; ksh < 2; ++ksh) {
        int ks = cb * 2 + ksh;
        s16x8 v = *(const s16x8*)&lsh[w * 1152 + (lane & 15) * 72 + ksh * 32 + (lane >> 4) * 8];
        ((s16x8*)Vp)[(rnt * 32 + ks) * 64 + lane] = v;
      }
    } else {
      const int g = blk - 256;                    // 0..11
      const int nfr = g * 4 + w;                  // 0..47
      const s16x8* XH = (const s16x8*)Xp;
      const s16x8* IH = (const s16x8*)Ip;
      f32x4 acc[4] = {};
      for (int ks = 0; ks < 32; ++ks) {
        s16x8 b = IH[(nfr * 32 + ks) * 64 + lane];
        #pragma unroll
        for (int mt = 0; mt < 4; ++mt)
          acc[mt] = __builtin_amdgcn_mfma_f32_16x16x32_bf16(XH[(mt * 32 + ks) * 64 + lane], b, acc[mt], 0, 0, 0);
      }
      const int d = nfr * 16 + (lane & 15);       // < 768
      const int dl = w * 16 + (lane & 15);
      const float be = b_emb[d];
      #pragma unroll
      for (int mt = 0; mt < 4; ++mt)
        #pragma unroll
        for (int rr = 0; rr < 4; ++rr) {
          int b = mt * 16 + (lane >> 4) * 4 + rr;
          float ev = acc[mt][rr] + be;
          emb[(size_t)b * DD + d] = ev;
          lsh[b * 72 + dl] = (short)f2bf_rne(ev);
        }
      __syncthreads();
      #pragma unroll
      for (int ksh = 0; ksh < 2; ++ksh) {
        int ks = g * 2 + ksh;                     // 0..23
        s16x8 v = *(const s16x8*)&lsh[(w * 16 + (lane & 15)) * 72 + ksh * 32 + (lane >> 4) * 8];
        ((s16x8*)Ep)[(w * 24 + ks) * 64 + lane] = v;
      }
    }
  }
  grid.sync();

  // ================= phase L: logits + AE + Pe + pred (blocks 0..63, wave w = mt) =================
  if (blk < 64) {
    const int nfr = blk, mt = w;
    const s16x8* E = (const s16x8*)Ep;
    const s16x8* B = (const s16x8*)Bp;
    const s16x8* A = (const s16x8*)Ap;
    f32x4 accL = {}, accA = {};
    for (int ks = 0; ks < 24; ++ks) {
      s16x8 a  = E[(mt * 24 + ks) * 64 + lane];
      s16x8 bW = B[(nfr * 24 + ks) * 64 + lane];
      s16x8 bA = A[(nfr * 24 + ks) * 64 + lane];
      accL = __builtin_amdgcn_mfma_f32_16x16x32_bf16(a, bW, accL, 0, 0, 0);
      accA = __builtin_amdgcn_mfma_f32_16x16x32_bf16(a, bA, accA, 0, 0, 0);
    }
    const int c = nfr * 16 + (lane & 15);
    const bool ok = (c < CC);
    const float bf = ok ? b_fc[c] : 0.f;
    float lv4[4];
    #pragma unroll
    for (int rr = 0; rr < 4; ++rr) {
      int blo = (lane >> 4) * 4 + rr;
      int b = mt * 16 + blo;
      float l = accL[rr] + bf;
      lv4[rr] = ok ? l : NEGINF;
      if (ok) {
        logits[b * CC + c] = l;
        AE[b * CC + c]     = accA[rr];
        size_t fi = ((size_t)(mt * 32 + (c >> 5)) * 64 + ((c >> 3) & 3) * 16 + blo) * 8 + (c & 7);
        Pe[fi] = (short)f2bf_rne(expf(l));
      }
    }
    #pragma unroll
    for (int rr = 0; rr < 4; ++rr) {
      float best = lv4[rr]; int bi = ok ? c : 0;
      #pragma unroll
      for (int o = 1; o < 16; o <<= 1) {
        float ov = __shfl_xor(best, o); int oi = __shfl_xor(bi, o);
        if (ov > best || (ov == best && oi < bi)) { best = ov; bi = oi; }
      }
      if ((lane & 15) == 0) {
        int b = mt * 16 + (lane >> 4) * 4 + rr;
        unsigned ub = __float_as_uint(best);
        ub = (ub & 0x80000000u) ? ~ub : (ub | 0x80000000u);
        atomicMax(amaxP + b, ((unsigned long long)ub << 32) |
                             (unsigned long long)(0xFFFFFFFFu - (unsigned)bi));
      }
    }
  }
  grid.sync();

  // ================= phase U: ue = e @ V (blocks 0..63, wave w = mt) =================
  if (blk < 64) {
    const int nfr = blk, mt = w;
    const s16x8* P = (const s16x8*)Pe;
    const s16x8* V = (const s16x8*)Vp;
    f32x4 acc = {};
    for (int ks = 0; ks < 32; ++ks) {
      s16x8 b = V[(nfr * 32 + ks) * 64 + lane];
      acc = __builtin_amdgcn_mfma_f32_16x16x32_bf16(P[(mt * 32 + ks) * 64 + lane], b, acc, 0, 0, 0);
    }
    const int c = nfr * 16 + (lane & 15);
    if (c < CC) {
      #pragma unroll
      for (int rr = 0; rr < 4; ++rr)
        ue[(mt * 16 + (lane >> 4) * 4 + rr) * CC + c] = acc[rr];
    }
  }
  grid.sync();

  // ================= phase S: per-b stats S, gsum, en2 (blocks 0..63) =================
  if (blk < 64) {
    const int b = blk;
    float* sred = (float*)smem;
    float gs = 0.f, ssum = 0.f, pe = 0.f;
    int cg2 = tid * 4;
    if (cg2 + 3 < CC) {
      float4 l4 = *(const float4*)(logits + b * CC + cg2);
      float4 u4 = *(const float4*)(ue + b * CC + cg2);
      float e0 = expf(l4.x), e1 = expf(l4.y), e2 = expf(l4.z), e3 = expf(l4.w);
      ssum += e0 + e1 + e2 + e3;
      gs += e0*u4.x + e1*u4.y + e2*u4.z + e3*u4.w;
    } else {
      #pragma unroll
      for (int i = 0; i < 4; ++i) {
        int c = cg2 + i;
        if (c < CC) {
          float e = expf(logits[b * CC + c]);
          ssum += e; gs += e * ue[b * CC + c];
        }
      }
    }
    if (cg2 + 3 < DD) {
      float4 em = *(const float4*)(emb + b * DD + cg2);
      pe += em.x*em.x + em.y*em.y + em.z*em.z + em.w*em.w;
    }
    #pragma unroll
    for (int o = 1; o < 64; o <<= 1) {
      gs += __shfl_xor(gs, o); ssum += __shfl_xor(ssum, o); pe += __shfl_xor(pe, o);
    }
    if (lane == 0) { sred[w] = gs; sred[4 + w] = ssum; sred[8 + w] = pe; }
    __syncthreads();
    if (tid == 0) {
      stats[b * 4 + 0] = sred[4] + sred[5] + sred[6] + sred[7];    // S
      stats[b * 4 + 1] = sred[0] + sred[1] + sred[2] + sred[3];    // gsum
      stats[b * 4 + 2] = sred[8] + sred[9] + sred[10] + sred[11];  // en2
    }
  }
  grid.sync();

  // ================= phase SCAN (all 512 blocks: b = blk>>3, cz = blk&7) =================
  {
    const int b = blk >> 3, cz = blk & 7;
    const int c0 = cz * 125;
    float2* LU = (float2*)smem;
    const float S    = stats[b * 4 + 0];
    const float gsum = stats[b * 4 + 1];
    const float en2  = stats[b * 4 + 2];
    const float Sinv = 1.0f / S;
    const float gS2  = gsum * Sinv * Sinv;
    if (tid < 125) {
      int c = c0 + tid;
      LU[tid] = float2{logits[b * CC + c], ue[b * CC + c] * Sinv};
    }
    __syncthreads();

    const int jt = (tid < 250 ? tid : 249) * 4;
    float4 an4 = *(const float4*)(An2 + jt);
    float4 ae4 = *(const float4*)(AE + b * CC + jt);
    float4 uj4 = *(const float4*)(ue + b * CC + jt);
    float sj[4], nsj[4];
    {
      float anv[4] = {an4.x, an4.y, an4.z, an4.w};
      float aev[4] = {ae4.x, ae4.y, ae4.z, ae4.w};
      float ujv[4] = {uj4.x * Sinv, uj4.y * Sinv, uj4.z * Sinv, uj4.w * Sinv};
      #pragma unroll
      for (int k = 0; k < 4; ++k) {
        float vd  = bf2f(Vb[(size_t)(jt + k) * 1024 + jt + k]);
        float zn2 = anv[k] - 2.0f * aev[k] + en2;
        float gn2 = gS2 - 2.0f * ujv[k] + vd;
        sj[k] = (EPSA * sqrtf(zn2)) / sqrtf(gn2);
        nsj[k] = -sj[k];
      }
    }

    float best[4] = {NEGINF, NEGINF, NEGINF, NEGINF};
    int   bi[4]   = {0, 0, 0, 0};
    const unsigned short* Vcol = Vb + jt;
    #pragma unroll 5
    for (int i = 0; i < 125; ++i) {
      int c = c0 + i;
      float2 lu = LU[i];                                   // broadcast (lane-uniform)
      uint2 vv = *(const uint2*)(Vcol + (size_t)c * 1024); // V[c][jt..jt+3], coalesced
      float v0 = __uint_as_float(vv.x << 16);
      float v1 = __uint_as_float(vv.x & 0xffff0000u);
      float v2 = __uint_as_float(vv.y << 16);
      float v3 = __uint_as_float(vv.y & 0xffff0000u);
      float t0 = fmaf(sj[0], lu.y, lu.x);
      float t1 = fmaf(sj[1], lu.y, lu.x);
      float t2 = fmaf(sj[2], lu.y, lu.x);
      float t3 = fmaf(sj[3], lu.y, lu.x);
      float val0 = fmaf(nsj[0], v0, t0);
      float val1 = fmaf(nsj[1], v1, t1);
      float val2 = fmaf(nsj[2], v2, t2);
      float val3 = fmaf(nsj[3], v3, t3);
      if (val0 > best[0]) { best[0] = val0; bi[0] = c; }   // ascending c + strict > = first max
      if (val1 > best[1]) { best[1] = val1; bi[1] = c; }
      if (val2 > best[2]) { best[2] = val2; bi[2] = c; }
      if (val3 > best[3]) { best[3] = val3; bi[3] = c; }
    }

    if (tid < 250) {
      unsigned long long* dst = part + ((size_t)(b * 1000 + jt)) * 8 + cz;
      #pragma unroll
      for (int k = 0; k < 4; ++k) {
        unsigned ub = __float_as_uint(best[k]);
        ub = (ub & 0x80000000u) ? ~ub : (ub | 0x80000000u);
        dst[(size_t)k * 8] = ((unsigned long long)ub << 32) |
                             (unsigned long long)(0xFFFFFFFFu - (unsigned)bi[k]);  // tie -> smaller c
      }
    }
  }
  grid.sync();

  // ================= phase C: counts (blocks 0..63) =================
  if (blk < 64) {
    const int b = blk;
    int* cnt = (int*)smem;                // 1001 ints (cnt[1000] = bad flag)
    for (int c = tid; c < CC; c += 256) cnt[c] = 0;
    if (tid == 0) cnt[CC] = 0;
    __syncthreads();
    if (tid == 0) {
      int predc = (int)(0xFFFFFFFFu - (unsigned)(amaxP[b] & 0xFFFFFFFFull));
      atomicAdd(&cnt[predc], 1);
    }
    for (int j = tid; j < CC; j += 256) {
      const unsigned long long* q = part + ((size_t)(b * 1000 + j)) * 8;   // contiguous 64B
      unsigned long long key = q[0];
      #pragma unroll
      for (int cz = 1; cz < 8; ++cz) {
        unsigned long long k2 = q[cz];
        key = (k2 > key) ? k2 : key;
      }
      int c = (int)(0xFFFFFFFFu - (unsigned)(key & 0xFFFFFFFFull));
      atomicAdd(&cnt[c], 1);
    }
    __syncthreads();
    for (int c = tid; c < CC; c += 256) if (cnt[c] >= NSIM) cnt[CC] = 1;
    __syncthreads();
    if (tid == 0) out[b] = cnt[CC] ? 0.0f : 1.0f;
  }
}

// ---------------------------------------------------------------- launch
extern "C" void kernel_launch(void* const* d_in, const int* in_sizes, int n_in,
                              void* d_out, int out_size, void* d_ws, size_t ws_size,
                              hipStream_t stream) {
  const float* x       = (const float*)d_in[0];
  const float* W_emb   = (const float*)d_in[1];
  const float* b_emb   = (const float*)d_in[2];
  const float* W_fc    = (const float*)d_in[3];
  const float* b_fc    = (const float*)d_in[4];
  const float* anchors = (const float*)d_in[5];
  float* out = (float*)d_out;

  // workspace carve (~14 MB), all aligned
  float* emb    = (float*)d_ws;               // 64*768
  float* logits = emb + BB * DD;              // 64*1000
  float* ue     = logits + BB * CC;           // 64*1000
  float* AE     = ue + BB * CC;               // 64*1000
  float* An2    = AE + BB * CC;               // 1024
  unsigned long long* amaxP = (unsigned long long*)(An2 + 1024);   // 64 u64
  float* stats  = (float*)(amaxP + 64);       // 256 floats
  unsigned long long* part  = (unsigned long long*)(stats + 256);  // 64000*8 u64 (4.1 MB), j-major
  short* Bp     = (short*)(part + 64000 * 8); // 786432 shorts
  short* Ap     = Bp + 64 * 24 * 64 * 8;      // 786432
  short* Ip     = Ap + 64 * 24 * 64 * 8;      // 786432
  short* Xp     = Ip + 48 * 32 * 64 * 8;      // 65536
  short* Ep     = Xp + 4 * 32 * 64 * 8;       // 49152
  short* Pe     = Ep + 4 * 24 * 64 * 8;       // 65536
  unsigned short* Vb = (unsigned short*)(Pe + 4 * 32 * 64 * 8);    // 1024*1024
  short* Vp     = (short*)(Vb + 1024 * 1024); // 1048576

  hipLaunchKernelGGL(prep_kernel, dim3(1435), dim3(256), 0, stream,
                     W_fc, anchors, W_emb, x, Bp, Ap, Ip, Xp, An2, amaxP, Pe);

  void* args[] = { (void*)&Bp, (void*)&Ip, (void*)&Xp, (void*)&b_emb, (void*)&Vb, (void*)&Vp,
                   (void*)&emb, (void*)&Ep, (void*)&Ap, (void*)&b_fc, (void*)&logits, (void*)&AE,
                   (void*)&Pe, (void*)&amaxP, (void*)&ue, (void*)&An2, (void*)&stats,
                   (void*)&part, (void*)&out };
  hipLaunchCooperativeKernel((void*)mega_kernel, dim3(512), dim3(256), args, 0, stream);
}

// Round 23
// 92.475 us; speedup vs baseline: 3.9036x; 3.9036x over previous
//
#include <hip/hip_runtime.h>
#include <stdint.h>
#include <stddef.h>

#define BB 64
#define DIN 1024
#define DD 768
#define CC 1000
#define EPSA 0.1f
#define NSIM 3
#define NEGINF -3.402823466e38f

typedef short  s16x8 __attribute__((ext_vector_type(8)));
typedef float  f32x4 __attribute__((ext_vector_type(4)));

static __device__ __forceinline__ unsigned short f2bf_rne(float x) {
  unsigned u = __float_as_uint(x);
  return (unsigned short)((u + 0x7FFFu + ((u >> 16) & 1u)) >> 16);
}
static __device__ __forceinline__ float bf2f(unsigned short h) {
  return __uint_as_float(((unsigned)h) << 16);
}

// ---------------------------------------------------------------- prep: pack {W_fc,anchors,W_emb,x} to bf16 frags + An2
// + tail block: zero amaxP, ready, and Pe k-pad slots (every replay)
__global__ __launch_bounds__(256) void prep_kernel(const float* __restrict__ W_fc,
                                                   const float* __restrict__ anchors,
                                                   const float* __restrict__ W_emb,
                                                   const float* __restrict__ x,
                                                   short* __restrict__ Bp, short* __restrict__ Ap,
                                                   short* __restrict__ Ip, short* __restrict__ Xp,
                                                   float* __restrict__ An2,
                                                   unsigned long long* __restrict__ amaxP,
                                                   unsigned int* __restrict__ ready,
                                                   short* __restrict__ Pe) {
  const int blk = blockIdx.x, tid = threadIdx.x;
  if (blk < 1184) {
    const float* src; short* dst; int KS, nrow, gid;
    if (blk < 384)       { src = W_fc;    dst = Bp; KS = 24; nrow = CC;  gid = blk * 256 + tid; }
    else if (blk < 768)  { src = anchors; dst = Ap; KS = 24; nrow = CC;  gid = (blk - 384) * 256 + tid; }
    else if (blk < 1152) { src = W_emb;   dst = Ip; KS = 32; nrow = DD;  gid = (blk - 768) * 256 + tid; }
    else                 { src = x;       dst = Xp; KS = 32; nrow = BB;  gid = (blk - 1152) * 256 + tid; }
    int lane = gid & 63;
    int ks   = (gid >> 6) % KS;
    int nt   = gid / (64 * KS);
    int row  = nt * 16 + (lane & 15);
    int k0   = ks * 32 + (lane >> 4) * 8;
    int stride = KS * 32;
    s16x8 v;
    #pragma unroll
    for (int r = 0; r < 8; ++r) {
      float w = (row < nrow) ? src[(size_t)row * stride + k0 + r] : 0.0f;
      v[r] = (short)f2bf_rne(w);
    }
    ((s16x8*)dst)[gid] = v;
  } else if (blk < 1434) {
    int w = tid >> 6, lane = tid & 63;
    int j = (blk - 1184) * 4 + w;          // < 1000
    const float4* ar = (const float4*)(anchors + (size_t)j * DD);
    float an = 0.f;
    for (int k4 = lane; k4 < DD / 4; k4 += 64) {
      float4 a = ar[k4];
      an += a.x*a.x + a.y*a.y + a.z*a.z + a.w*a.w;
    }
    #pragma unroll
    for (int o = 1; o < 64; o <<= 1) an += __shfl_xor(an, o);
    if (lane == 0) An2[j] = an;
  } else {
    if (tid < 64) { amaxP[tid] = 0ull; ready[tid] = 0u; }
    for (int idx = tid; idx < 1536; idx += 256) {   // Pe pads: c = 1000..1023 for each b
      int b = idx / 24, cp = 1000 + idx % 24;
      int mt = b >> 4, blo = b & 15;
      size_t fi = ((size_t)(mt * 32 + (cp >> 5)) * 64 + ((cp >> 3) & 3) * 16 + blo) * 8 + (cp & 7);
      Pe[fi] = 0;
    }
  }
}

// ---------------------------------------------------------------- embV: blocks 0..255 -> Vb + Vp; 256..267 -> emb + Ep
__global__ __launch_bounds__(256) void embV_kernel(const short* __restrict__ Bp,
                                                   const short* __restrict__ Ip,
                                                   const short* __restrict__ Xp,
                                                   const float* __restrict__ b_emb,
                                                   unsigned short* __restrict__ Vb,
                                                   short* __restrict__ Vp,
                                                   float* __restrict__ emb,
                                                   short* __restrict__ Ep) {
  const int tid = threadIdx.x, w = tid >> 6, lane = tid & 63;
  __shared__ __attribute__((aligned(16))) short lsh[4608];   // V: [4][16][72], emb: [64][72]
  if (blockIdx.x < 256) {
    const int bx = blockIdx.x & 15, cb = blockIdx.x >> 4;
    const int rnt = bx * 4 + w;
    const s16x8* BH = (const s16x8*)Bp;
    f32x4 acc[4] = {};
    for (int ks = 0; ks < 24; ++ks) {
      s16x8 a = BH[(rnt * 24 + ks) * 64 + lane];
      #pragma unroll
      for (int nf = 0; nf < 4; ++nf)
        acc[nf] = __builtin_amdgcn_mfma_f32_16x16x32_bf16(a, BH[((cb * 4 + nf) * 24 + ks) * 64 + lane], acc[nf], 0, 0, 0);
    }
    const int rl0 = (lane >> 4) * 4;             // C/D: row=(lane>>4)*4+reg, col=lane&15 [m89]
    const int r0 = rnt * 16 + rl0;
    const int c0 = cb * 64 + (lane & 15);
    #pragma unroll
    for (int nf = 0; nf < 4; ++nf)
      #pragma unroll
      for (int rr = 0; rr < 4; ++rr) {
        unsigned short h = f2bf_rne(acc[nf][rr]);
        Vb[(size_t)(r0 + rr) * 1024 + c0 + nf * 16] = h;
        lsh[w * 1152 + (rl0 + rr) * 72 + (lane & 15) + nf * 16] = (short)h;
      }
    __syncthreads();
    #pragma unroll
    for (int ksh = 0; ksh < 2; ++ksh) {
      int ks = cb * 2 + ksh;
      s16x8 v = *(const s16x8*)&lsh[w * 1152 + (lane & 15) * 72 + ksh * 32 + (lane >> 4) * 8];
      ((s16x8*)Vp)[(rnt * 32 + ks) * 64 + lane] = v;
    }
  } else {
    const int g = blockIdx.x - 256;             // 0..11
    const int nfr = g * 4 + w;                  // 0..47
    const s16x8* XH = (const s16x8*)Xp;
    const s16x8* IH = (const s16x8*)Ip;
    f32x4 acc[4] = {};
    for (int ks = 0; ks < 32; ++ks) {
      s16x8 b = IH[(nfr * 32 + ks) * 64 + lane];
      #pragma unroll
      for (int mt = 0; mt < 4; ++mt)
        acc[mt] = __builtin_amdgcn_mfma_f32_16x16x32_bf16(XH[(mt * 32 + ks) * 64 + lane], b, acc[mt], 0, 0, 0);
    }
    const int d = nfr * 16 + (lane & 15);       // < 768
    const int dl = w * 16 + (lane & 15);
    const float be = b_emb[d];
    #pragma unroll
    for (int mt = 0; mt < 4; ++mt)
      #pragma unroll
      for (int rr = 0; rr < 4; ++rr) {
        int b = mt * 16 + (lane >> 4) * 4 + rr;
        float ev = acc[mt][rr] + be;
        emb[(size_t)b * DD + d] = ev;
        lsh[b * 72 + dl] = (short)f2bf_rne(ev);
      }
    __syncthreads();
    #pragma unroll
    for (int ksh = 0; ksh < 2; ++ksh) {
      int ks = g * 2 + ksh;                     // 0..23
      int mt2 = tid >> 6;
      s16x8 v = *(const s16x8*)&lsh[(mt2 * 16 + (lane & 15)) * 72 + ksh * 32 + (lane >> 4) * 8];
      ((s16x8*)Ep)[(mt2 * 24 + ks) * 64 + lane] = v;
    }
  }
}

// ---------------------------------------------------------------- logits + AE + Pe=bf16(exp(l)) + pred partial (grid 64 x 4)
__global__ __launch_bounds__(64) void logitsAE_kernel(const short* __restrict__ Ep,
                                                      const short* __restrict__ Bp,
                                                      const short* __restrict__ Ap,
                                                      const float* __restrict__ b_fc,
                                                      float* __restrict__ logits,
                                                      float* __restrict__ AE,
                                                      short* __restrict__ Pe,
                                                      unsigned long long* __restrict__ amaxP) {
  const int nfr = blockIdx.x;                  // 0..63
  const int mt  = blockIdx.y;                  // 0..3
  const int lane = threadIdx.x;
  const s16x8* E = (const s16x8*)Ep;
  const s16x8* B = (const s16x8*)Bp;
  const s16x8* A = (const s16x8*)Ap;
  f32x4 accL = {}, accA = {};
  for (int ks = 0; ks < 24; ++ks) {
    s16x8 a  = E[(mt * 24 + ks) * 64 + lane];
    s16x8 bW = B[(nfr * 24 + ks) * 64 + lane];
    s16x8 bA = A[(nfr * 24 + ks) * 64 + lane];
    accL = __builtin_amdgcn_mfma_f32_16x16x32_bf16(a, bW, accL, 0, 0, 0);
    accA = __builtin_amdgcn_mfma_f32_16x16x32_bf16(a, bA, accA, 0, 0, 0);
  }
  const int c = nfr * 16 + (lane & 15);
  const bool ok = (c < CC);
  const float bf = ok ? b_fc[c] : 0.f;
  float lv4[4];
  #pragma unroll
  for (int rr = 0; rr < 4; ++rr) {
    int blo = (lane >> 4) * 4 + rr;
    int b = mt * 16 + blo;
    float l = accL[rr] + bf;
    lv4[rr] = ok ? l : NEGINF;
    if (ok) {
      logits[b * CC + c] = l;
      AE[b * CC + c]     = accA[rr];
      size_t fi = ((size_t)(mt * 32 + (c >> 5)) * 64 + ((c >> 3) & 3) * 16 + blo) * 8 + (c & 7);
      Pe[fi] = (short)f2bf_rne(expf(l));
    }
  }
  // pred partial: reduce over the 16 c-lanes per b-row, one atomicMax per row
  #pragma unroll
  for (int rr = 0; rr < 4; ++rr) {
    float best = lv4[rr]; int bi = ok ? c : 0;
    #pragma unroll
    for (int o = 1; o < 16; o <<= 1) {
      float ov = __shfl_xor(best, o); int oi = __shfl_xor(bi, o);
      if (ov > best || (ov == best && oi < bi)) { best = ov; bi = oi; }
    }
    if ((lane & 15) == 0) {
      int b = mt * 16 + (lane >> 4) * 4 + rr;
      unsigned ub = __float_as_uint(best);
      ub = (ub & 0x80000000u) ? ~ub : (ub | 0x80000000u);
      atomicMax(amaxP + b, ((unsigned long long)ub << 32) |
                           (unsigned long long)(0xFFFFFFFFu - (unsigned)bi));
    }
  }
}

// ---------------------------------------------------------------- ue = e @ V via MFMA (grid 64 x 4, 1 wave)
__global__ __launch_bounds__(64) void u_kernel(const short* __restrict__ Pe,
                                               const short* __restrict__ Vp,
                                               float* __restrict__ ue) {
  const int nfr = blockIdx.x;                  // 0..63
  const int mt  = blockIdx.y;                  // 0..3
  const int lane = threadIdx.x;
  const s16x8* P = (const s16x8*)Pe;
  const s16x8* V = (const s16x8*)Vp;
  f32x4 acc = {};
  for (int ks = 0; ks < 32; ++ks) {
    s16x8 b = V[(nfr * 32 + ks) * 64 + lane];
    acc = __builtin_amdgcn_mfma_f32_16x16x32_bf16(P[(mt * 32 + ks) * 64 + lane], b, acc, 0, 0, 0);
  }
  const int c = nfr * 16 + (lane & 15);
  if (c < CC) {
    #pragma unroll
    for (int rr = 0; rr < 4; ++rr)
      ue[(mt * 16 + (lane >> 4) * 4 + rr) * CC + c] = acc[rr];
  }
}

// ---------------------------------------------------------------- scan + last-block counts merge
// grid (64, 8). part[(b*1000+j)*8 + cz]; 8th-arriving block per b does counts.
__global__ __launch_bounds__(256) void scan_kernel(const float* __restrict__ logits,
                                                   const float* __restrict__ ue,
                                                   const float* __restrict__ emb,
                                                   const float* __restrict__ AE,
                                                   const float* __restrict__ An2,
                                                   const unsigned short* __restrict__ Vb,
                                                   unsigned long long* __restrict__ part,
                                                   unsigned long long* __restrict__ amaxP,
                                                   unsigned int* __restrict__ ready,
                                                   float* __restrict__ out) {
  const int b = blockIdx.x, cz = blockIdx.y;   // cz < 8
  const int tid = threadIdx.x;
  const int c0 = cz * 125;
  __shared__ __attribute__((aligned(8))) float2 LU[128];
  __shared__ float se[4], sg[4], sn[4];
  __shared__ int sLast;

  // fixed-order reductions: S = sum e, gsum = sum e*ue, en2 = ||emb||^2
  float gs = 0.f, ss = 0.f, pe = 0.f;
  {
    int cg = tid * 4;
    if (cg + 3 < CC) {
      float4 l4 = *(const float4*)(logits + b * CC + cg);
      float4 u4 = *(const float4*)(ue + b * CC + cg);
      float e0 = expf(l4.x), e1 = expf(l4.y), e2 = expf(l4.z), e3 = expf(l4.w);
      ss += e0 + e1 + e2 + e3;
      gs += e0*u4.x + e1*u4.y + e2*u4.z + e3*u4.w;
    } else {
      #pragma unroll
      for (int i = 0; i < 4; ++i) {
        int c = cg + i;
        if (c < CC) {
          float e = expf(logits[b * CC + c]);
          ss += e; gs += e * ue[b * CC + c];
        }
      }
    }
    if (cg + 3 < DD) {   // DD=768: tid<192
      float4 em = *(const float4*)(emb + b * DD + cg);
      pe += em.x*em.x + em.y*em.y + em.z*em.z + em.w*em.w;
    }
  }
  #pragma unroll
  for (int o = 1; o < 64; o <<= 1) {
    gs += __shfl_xor(gs, o); ss += __shfl_xor(ss, o); pe += __shfl_xor(pe, o);
  }
  if ((tid & 63) == 0) { int w = tid >> 6; se[w] = gs; sg[w] = ss; sn[w] = pe; }
  __syncthreads();
  const float gsum = se[0] + se[1] + se[2] + se[3];
  const float S    = sg[0] + sg[1] + sg[2] + sg[3];
  const float en2  = sn[0] + sn[1] + sn[2] + sn[3];
  const float Sinv = 1.0f / S;
  const float gS2  = gsum * Sinv * Sinv;       // = Gn2 base (sum p*u)

  if (tid < 125) {
    int c = c0 + tid;
    LU[tid] = float2{logits[b * CC + c], ue[b * CC + c] * Sinv};
  }
  __syncthreads();

  // this thread's 4 j's (threads 250..255 duplicate 249, don't write)
  const int jt = (tid < 250 ? tid : 249) * 4;
  float4 an4 = *(const float4*)(An2 + jt);
  float4 ae4 = *(const float4*)(AE + b * CC + jt);
  float4 uj4 = *(const float4*)(ue + b * CC + jt);
  float sj[4], nsj[4];
  {
    float anv[4] = {an4.x, an4.y, an4.z, an4.w};
    float aev[4] = {ae4.x, ae4.y, ae4.z, ae4.w};
    float ujv[4] = {uj4.x * Sinv, uj4.y * Sinv, uj4.z * Sinv, uj4.w * Sinv};
    #pragma unroll
    for (int k = 0; k < 4; ++k) {
      float vd  = bf2f(Vb[(size_t)(jt + k) * 1024 + jt + k]);
      float zn2 = anv[k] - 2.0f * aev[k] + en2;
      float gn2 = gS2 - 2.0f * ujv[k] + vd;
      sj[k] = (EPSA * sqrtf(zn2)) / sqrtf(gn2);
      nsj[k] = -sj[k];
    }
  }

  float best[4] = {NEGINF, NEGINF, NEGINF, NEGINF};
  int   bi[4]   = {0, 0, 0, 0};
  const unsigned short* Vcol = Vb + jt;
  #pragma unroll 5
  for (int i = 0; i < 125; ++i) {
    int c = c0 + i;
    float2 lu = LU[i];                                   // broadcast (lane-uniform)
    uint2 vv = *(const uint2*)(Vcol + (size_t)c * 1024); // V[c][jt..jt+3], coalesced
    float v0 = __uint_as_float(vv.x << 16);
    float v1 = __uint_as_float(vv.x & 0xffff0000u);
    float v2 = __uint_as_float(vv.y << 16);
    float v3 = __uint_as_float(vv.y & 0xffff0000u);
    float t0 = fmaf(sj[0], lu.y, lu.x);
    float t1 = fmaf(sj[1], lu.y, lu.x);
    float t2 = fmaf(sj[2], lu.y, lu.x);
    float t3 = fmaf(sj[3], lu.y, lu.x);
    float val0 = fmaf(nsj[0], v0, t0);
    float val1 = fmaf(nsj[1], v1, t1);
    float val2 = fmaf(nsj[2], v2, t2);
    float val3 = fmaf(nsj[3], v3, t3);
    if (val0 > best[0]) { best[0] = val0; bi[0] = c; }   // ascending c + strict > = first max
    if (val1 > best[1]) { best[1] = val1; bi[1] = c; }
    if (val2 > best[2]) { best[2] = val2; bi[2] = c; }
    if (val3 > best[3]) { best[3] = val3; bi[3] = c; }
  }

  if (tid < 250) {
    unsigned long long* dst = part + ((size_t)(b * 1000 + jt)) * 8 + cz;
    #pragma unroll
    for (int k = 0; k < 4; ++k) {
      unsigned ub = __float_as_uint(best[k]);
      ub = (ub & 0x80000000u) ? ~ub : (ub | 0x80000000u);
      dst[(size_t)k * 8] = ((unsigned long long)ub << 32) |
                           (unsigned long long)(0xFFFFFFFFu - (unsigned)bi[k]);  // tie -> smaller c
    }
  }

  // -------- last-block-per-b counts merge (deadlock-free, order-independent) --------
  __syncthreads();                 // all part stores issued & drained (vmcnt at barrier)
  if (tid == 0) {
    __threadfence();               // release: make this block's stores device-visible
    unsigned prev = atomicAdd(&ready[b], 1u);
    sLast = (prev == 7u) ? 1 : 0;
  }
  __syncthreads();
  if (!sLast) return;
  if (tid == 0) __threadfence();   // acquire: invalidate so we see other blocks' slices
  __syncthreads();

  __shared__ int cnt[CC + 1];      // cnt[CC] = bad flag
  for (int c = tid; c < CC; c += 256) cnt[c] = 0;
  if (tid == 0) cnt[CC] = 0;
  __syncthreads();
  if (tid == 0) {
    int predc = (int)(0xFFFFFFFFu - (unsigned)(amaxP[b] & 0xFFFFFFFFull));
    atomicAdd(&cnt[predc], 1);
  }
  for (int j = tid; j < CC; j += 256) {
    const unsigned long long* q = part + ((size_t)(b * 1000 + j)) * 8;   // contiguous 64B
    unsigned long long key = q[0];
    #pragma unroll
    for (int cz2 = 1; cz2 < 8; ++cz2) {
      unsigned long long k2 = q[cz2];
      key = (k2 > key) ? k2 : key;
    }
    int c = (int)(0xFFFFFFFFu - (unsigned)(key & 0xFFFFFFFFull));
    atomicAdd(&cnt[c], 1);
  }
  __syncthreads();
  for (int c = tid; c < CC; c += 256) if (cnt[c] >= NSIM) cnt[CC] = 1;
  __syncthreads();
  if (tid == 0) out[b] = cnt[CC] ? 0.0f : 1.0f;
}

// ---------------------------------------------------------------- launch
extern "C" void kernel_launch(void* const* d_in, const int* in_sizes, int n_in,
                              void* d_out, int out_size, void* d_ws, size_t ws_size,
                              hipStream_t stream) {
  const float* x       = (const float*)d_in[0];
  const float* W_emb   = (const float*)d_in[1];
  const float* b_emb   = (const float*)d_in[2];
  const float* W_fc    = (const float*)d_in[3];
  const float* b_fc    = (const float*)d_in[4];
  const float* anchors = (const float*)d_in[5];
  float* out = (float*)d_out;

  // workspace carve (~14 MB), all aligned
  float* emb    = (float*)d_ws;               // 64*768
  float* logits = emb + BB * DD;              // 64*1000
  float* ue     = logits + BB * CC;           // 64*1000
  float* AE     = ue + BB * CC;               // 64*1000
  float* An2    = AE + BB * CC;               // 1024
  unsigned long long* amaxP = (unsigned long long*)(An2 + 1024);   // 64 u64
  unsigned int* ready = (unsigned int*)(amaxP + 64);               // 64 u32
  unsigned long long* part  = (unsigned long long*)(ready + 64);   // 64000*8 u64 (4.1 MB), j-major
  short* Bp     = (short*)(part + 64000 * 8); // 786432 shorts
  short* Ap     = Bp + 64 * 24 * 64 * 8;      // 786432
  short* Ip     = Ap + 64 * 24 * 64 * 8;      // 786432
  short* Xp     = Ip + 48 * 32 * 64 * 8;      // 65536
  short* Ep     = Xp + 4 * 32 * 64 * 8;       // 49152
  short* Pe     = Ep + 4 * 24 * 64 * 8;       // 65536
  unsigned short* Vb = (unsigned short*)(Pe + 4 * 32 * 64 * 8);    // 1024*1024
  short* Vp     = (short*)(Vb + 1024 * 1024); // 1048576

  hipLaunchKernelGGL(prep_kernel,    dim3(1435), dim3(256), 0, stream,
                     W_fc, anchors, W_emb, x, Bp, Ap, Ip, Xp, An2, amaxP, ready, Pe);
  hipLaunchKernelGGL(embV_kernel,    dim3(268), dim3(256), 0, stream,
                     Bp, Ip, Xp, b_emb, Vb, Vp, emb, Ep);
  hipLaunchKernelGGL(logitsAE_kernel,dim3(64, 4), dim3(64), 0, stream,
                     Ep, Bp, Ap, b_fc, logits, AE, Pe, amaxP);
  hipLaunchKernelGGL(u_kernel,       dim3(64, 4), dim3(64), 0, stream, Pe, Vp, ue);
  hipLaunchKernelGGL(scan_kernel,    dim3(BB, 8), dim3(256), 0, stream,
                     logits, ue, emb, AE, An2, Vb, part, amaxP, ready, out);
}

// Round 24
// 71.362 us; speedup vs baseline: 5.0585x; 1.2959x over previous
//
#include <hip/hip_runtime.h>
#include <stdint.h>
#include <stddef.h>

#define BB 64
#define DIN 1024
#define DD 768
#define CC 1000
#define EPSA 0.1f
#define NSIM 3
#define NEGINF -3.402823466e38f

typedef short  s16x8 __attribute__((ext_vector_type(8)));
typedef float  f32x4 __attribute__((ext_vector_type(4)));

static __device__ __forceinline__ unsigned short f2bf_rne(float x) {
  unsigned u = __float_as_uint(x);
  return (unsigned short)((u + 0x7FFFu + ((u >> 16) & 1u)) >> 16);
}
static __device__ __forceinline__ float bf2f(unsigned short h) {
  return __uint_as_float(((unsigned)h) << 16);
}

// ---------------------------------------------------------------- prep: pack {W_fc,anchors,W_emb,x} to bf16 frags + An2
// + tail block: zero amaxP and Pe k-pad slots (every replay)
__global__ __launch_bounds__(256) void prep_kernel(const float* __restrict__ W_fc,
                                                   const float* __restrict__ anchors,
                                                   const float* __restrict__ W_emb,
                                                   const float* __restrict__ x,
                                                   short* __restrict__ Bp, short* __restrict__ Ap,
                                                   short* __restrict__ Ip, short* __restrict__ Xp,
                                                   float* __restrict__ An2,
                                                   unsigned long long* __restrict__ amaxP,
                                                   short* __restrict__ Pe) {
  const int blk = blockIdx.x, tid = threadIdx.x;
  if (blk < 1184) {
    const float* src; short* dst; int KS, nrow, gid;
    if (blk < 384)       { src = W_fc;    dst = Bp; KS = 24; nrow = CC;  gid = blk * 256 + tid; }
    else if (blk < 768)  { src = anchors; dst = Ap; KS = 24; nrow = CC;  gid = (blk - 384) * 256 + tid; }
    else if (blk < 1152) { src = W_emb;   dst = Ip; KS = 32; nrow = DD;  gid = (blk - 768) * 256 + tid; }
    else                 { src = x;       dst = Xp; KS = 32; nrow = BB;  gid = (blk - 1152) * 256 + tid; }
    int lane = gid & 63;
    int ks   = (gid >> 6) % KS;
    int nt   = gid / (64 * KS);
    int row  = nt * 16 + (lane & 15);
    int k0   = ks * 32 + (lane >> 4) * 8;
    int stride = KS * 32;
    s16x8 v;
    #pragma unroll
    for (int r = 0; r < 8; ++r) {
      float w = (row < nrow) ? src[(size_t)row * stride + k0 + r] : 0.0f;
      v[r] = (short)f2bf_rne(w);
    }
    ((s16x8*)dst)[gid] = v;
  } else if (blk < 1434) {
    int w = tid >> 6, lane = tid & 63;
    int j = (blk - 1184) * 4 + w;          // < 1000
    const float4* ar = (const float4*)(anchors + (size_t)j * DD);
    float an = 0.f;
    for (int k4 = lane; k4 < DD / 4; k4 += 64) {
      float4 a = ar[k4];
      an += a.x*a.x + a.y*a.y + a.z*a.z + a.w*a.w;
    }
    #pragma unroll
    for (int o = 1; o < 64; o <<= 1) an += __shfl_xor(an, o);
    if (lane == 0) An2[j] = an;
  } else {
    if (tid < 64) amaxP[tid] = 0ull;
    for (int idx = tid; idx < 1536; idx += 256) {   // Pe pads: c = 1000..1023 for each b
      int b = idx / 24, cp = 1000 + idx % 24;
      int mt = b >> 4, blo = b & 15;
      size_t fi = ((size_t)(mt * 32 + (cp >> 5)) * 64 + ((cp >> 3) & 3) * 16 + blo) * 8 + (cp & 7);
      Pe[fi] = 0;
    }
  }
}

// ---------------------------------------------------------------- embV: blocks 0..255 -> Vb + Vp; 256..267 -> emb + Ep
__global__ __launch_bounds__(256) void embV_kernel(const short* __restrict__ Bp,
                                                   const short* __restrict__ Ip,
                                                   const short* __restrict__ Xp,
                                                   const float* __restrict__ b_emb,
                                                   unsigned short* __restrict__ Vb,
                                                   short* __restrict__ Vp,
                                                   float* __restrict__ emb,
                                                   short* __restrict__ Ep) {
  const int tid = threadIdx.x, w = tid >> 6, lane = tid & 63;
  __shared__ __attribute__((aligned(16))) short lsh[4608];   // V: [4][16][72], emb: [64][72]
  if (blockIdx.x < 256) {
    const int bx = blockIdx.x & 15, cb = blockIdx.x >> 4;
    const int rnt = bx * 4 + w;
    const s16x8* BH = (const s16x8*)Bp;
    f32x4 acc[4] = {};
    for (int ks = 0; ks < 24; ++ks) {
      s16x8 a = BH[(rnt * 24 + ks) * 64 + lane];
      #pragma unroll
      for (int nf = 0; nf < 4; ++nf)
        acc[nf] = __builtin_amdgcn_mfma_f32_16x16x32_bf16(a, BH[((cb * 4 + nf) * 24 + ks) * 64 + lane], acc[nf], 0, 0, 0);
    }
    const int rl0 = (lane >> 4) * 4;             // C/D: row=(lane>>4)*4+reg, col=lane&15 [m89]
    const int r0 = rnt * 16 + rl0;
    const int c0 = cb * 64 + (lane & 15);
    #pragma unroll
    for (int nf = 0; nf < 4; ++nf)
      #pragma unroll
      for (int rr = 0; rr < 4; ++rr) {
        unsigned short h = f2bf_rne(acc[nf][rr]);
        Vb[(size_t)(r0 + rr) * 1024 + c0 + nf * 16] = h;
        lsh[w * 1152 + (rl0 + rr) * 72 + (lane & 15) + nf * 16] = (short)h;
      }
    __syncthreads();
    #pragma unroll
    for (int ksh = 0; ksh < 2; ++ksh) {
      int ks = cb * 2 + ksh;
      s16x8 v = *(const s16x8*)&lsh[w * 1152 + (lane & 15) * 72 + ksh * 32 + (lane >> 4) * 8];
      ((s16x8*)Vp)[(rnt * 32 + ks) * 64 + lane] = v;
    }
  } else {
    const int g = blockIdx.x - 256;             // 0..11
    const int nfr = g * 4 + w;                  // 0..47
    const s16x8* XH = (const s16x8*)Xp;
    const s16x8* IH = (const s16x8*)Ip;
    f32x4 acc[4] = {};
    for (int ks = 0; ks < 32; ++ks) {
      s16x8 b = IH[(nfr * 32 + ks) * 64 + lane];
      #pragma unroll
      for (int mt = 0; mt < 4; ++mt)
        acc[mt] = __builtin_amdgcn_mfma_f32_16x16x32_bf16(XH[(mt * 32 + ks) * 64 + lane], b, acc[mt], 0, 0, 0);
    }
    const int d = nfr * 16 + (lane & 15);       // < 768
    const int dl = w * 16 + (lane & 15);
    const float be = b_emb[d];
    #pragma unroll
    for (int mt = 0; mt < 4; ++mt)
      #pragma unroll
      for (int rr = 0; rr < 4; ++rr) {
        int b = mt * 16 + (lane >> 4) * 4 + rr;
        float ev = acc[mt][rr] + be;
        emb[(size_t)b * DD + d] = ev;
        lsh[b * 72 + dl] = (short)f2bf_rne(ev);
      }
    __syncthreads();
    #pragma unroll
    for (int ksh = 0; ksh < 2; ++ksh) {
      int ks = g * 2 + ksh;                     // 0..23
      int mt2 = tid >> 6;
      s16x8 v = *(const s16x8*)&lsh[(mt2 * 16 + (lane & 15)) * 72 + ksh * 32 + (lane >> 4) * 8];
      ((s16x8*)Ep)[(mt2 * 24 + ks) * 64 + lane] = v;
    }
  }
}

// ---------------------------------------------------------------- logits + AE + Pe=bf16(exp(l)) + pred partial (grid 64 x 4)
__global__ __launch_bounds__(64) void logitsAE_kernel(const short* __restrict__ Ep,
                                                      const short* __restrict__ Bp,
                                                      const short* __restrict__ Ap,
                                                      const float* __restrict__ b_fc,
                                                      float* __restrict__ logits,
                                                      float* __restrict__ AE,
                                                      short* __restrict__ Pe,
                                                      unsigned long long* __restrict__ amaxP) {
  const int nfr = blockIdx.x;                  // 0..63
  const int mt  = blockIdx.y;                  // 0..3
  const int lane = threadIdx.x;
  const s16x8* E = (const s16x8*)Ep;
  const s16x8* B = (const s16x8*)Bp;
  const s16x8* A = (const s16x8*)Ap;
  f32x4 accL = {}, accA = {};
  for (int ks = 0; ks < 24; ++ks) {
    s16x8 a  = E[(mt * 24 + ks) * 64 + lane];
    s16x8 bW = B[(nfr * 24 + ks) * 64 + lane];
    s16x8 bA = A[(nfr * 24 + ks) * 64 + lane];
    accL = __builtin_amdgcn_mfma_f32_16x16x32_bf16(a, bW, accL, 0, 0, 0);
    accA = __builtin_amdgcn_mfma_f32_16x16x32_bf16(a, bA, accA, 0, 0, 0);
  }
  const int c = nfr * 16 + (lane & 15);
  const bool ok = (c < CC);
  const float bf = ok ? b_fc[c] : 0.f;
  float lv4[4];
  #pragma unroll
  for (int rr = 0; rr < 4; ++rr) {
    int blo = (lane >> 4) * 4 + rr;
    int b = mt * 16 + blo;
    float l = accL[rr] + bf;
    lv4[rr] = ok ? l : NEGINF;
    if (ok) {
      logits[b * CC + c] = l;
      AE[b * CC + c]     = accA[rr];
      size_t fi = ((size_t)(mt * 32 + (c >> 5)) * 64 + ((c >> 3) & 3) * 16 + blo) * 8 + (c & 7);
      Pe[fi] = (short)f2bf_rne(expf(l));
    }
  }
  // pred partial: reduce over the 16 c-lanes per b-row, one atomicMax per row
  #pragma unroll
  for (int rr = 0; rr < 4; ++rr) {
    float best = lv4[rr]; int bi = ok ? c : 0;
    #pragma unroll
    for (int o = 1; o < 16; o <<= 1) {
      float ov = __shfl_xor(best, o); int oi = __shfl_xor(bi, o);
      if (ov > best || (ov == best && oi < bi)) { best = ov; bi = oi; }
    }
    if ((lane & 15) == 0) {
      int b = mt * 16 + (lane >> 4) * 4 + rr;
      unsigned ub = __float_as_uint(best);
      ub = (ub & 0x80000000u) ? ~ub : (ub | 0x80000000u);
      atomicMax(amaxP + b, ((unsigned long long)ub << 32) |
                           (unsigned long long)(0xFFFFFFFFu - (unsigned)bi));
    }
  }
}

// ---------------------------------------------------------------- ue = e @ V via MFMA (grid 64 x 4, 1 wave)
__global__ __launch_bounds__(64) void u_kernel(const short* __restrict__ Pe,
                                               const short* __restrict__ Vp,
                                               float* __restrict__ ue) {
  const int nfr = blockIdx.x;                  // 0..63
  const int mt  = blockIdx.y;                  // 0..3
  const int lane = threadIdx.x;
  const s16x8* P = (const s16x8*)Pe;
  const s16x8* V = (const s16x8*)Vp;
  f32x4 acc = {};
  for (int ks = 0; ks < 32; ++ks) {
    s16x8 b = V[(nfr * 32 + ks) * 64 + lane];
    acc = __builtin_amdgcn_mfma_f32_16x16x32_bf16(P[(mt * 32 + ks) * 64 + lane], b, acc, 0, 0, 0);
  }
  const int c = nfr * 16 + (lane & 15);
  if (c < CC) {
    #pragma unroll
    for (int rr = 0; rr < 4; ++rr)
      ue[(mt * 16 + (lane >> 4) * 4 + rr) * CC + c] = acc[rr];
  }
}

// ---------------------------------------------------------------- scan: S, Σe·ue, En2 in-block; thread owns 4 j's; j-major partials
// grid (64, 8). part[(b*1000+j)*8 + cz].
__global__ __launch_bounds__(256) void scan_kernel(const float* __restrict__ logits,
                                                   const float* __restrict__ ue,
                                                   const float* __restrict__ emb,
                                                   const float* __restrict__ AE,
                                                   const float* __restrict__ An2,
                                                   const unsigned short* __restrict__ Vb,
                                                   unsigned long long* __restrict__ part) {
  const int b = blockIdx.x, cz = blockIdx.y;   // cz < 8
  const int tid = threadIdx.x;
  const int c0 = cz * 125;
  __shared__ __attribute__((aligned(8))) float2 LU[128];
  __shared__ float se[4], sg[4], sn[4];

  // fixed-order reductions: S = sum e, gsum = sum e*ue, en2 = ||emb||^2
  float gs = 0.f, ss = 0.f, pe = 0.f;
  {
    int cg = tid * 4;
    if (cg + 3 < CC) {
      float4 l4 = *(const float4*)(logits + b * CC + cg);
      float4 u4 = *(const float4*)(ue + b * CC + cg);
      float e0 = expf(l4.x), e1 = expf(l4.y), e2 = expf(l4.z), e3 = expf(l4.w);
      ss += e0 + e1 + e2 + e3;
      gs += e0*u4.x + e1*u4.y + e2*u4.z + e3*u4.w;
    } else {
      #pragma unroll
      for (int i = 0; i < 4; ++i) {
        int c = cg + i;
        if (c < CC) {
          float e = expf(logits[b * CC + c]);
          ss += e; gs += e * ue[b * CC + c];
        }
      }
    }
    if (cg + 3 < DD) {   // DD=768: tid<192
      float4 em = *(const float4*)(emb + b * DD + cg);
      pe += em.x*em.x + em.y*em.y + em.z*em.z + em.w*em.w;
    }
  }
  #pragma unroll
  for (int o = 1; o < 64; o <<= 1) {
    gs += __shfl_xor(gs, o); ss += __shfl_xor(ss, o); pe += __shfl_xor(pe, o);
  }
  if ((tid & 63) == 0) { int w = tid >> 6; se[w] = gs; sg[w] = ss; sn[w] = pe; }
  __syncthreads();
  const float gsum = se[0] + se[1] + se[2] + se[3];
  const float S    = sg[0] + sg[1] + sg[2] + sg[3];
  const float en2  = sn[0] + sn[1] + sn[2] + sn[3];
  const float Sinv = 1.0f / S;
  const float gS2  = gsum * Sinv * Sinv;       // = Gn2 base (sum p*u)

  if (tid < 125) {
    int c = c0 + tid;
    LU[tid] = float2{logits[b * CC + c], ue[b * CC + c] * Sinv};
  }
  __syncthreads();

  // this thread's 4 j's (threads 250..255 duplicate 249, don't write)
  const int jt = (tid < 250 ? tid : 249) * 4;
  float4 an4 = *(const float4*)(An2 + jt);
  float4 ae4 = *(const float4*)(AE + b * CC + jt);
  float4 uj4 = *(const float4*)(ue + b * CC + jt);
  float sj[4], nsj[4];
  {
    float anv[4] = {an4.x, an4.y, an4.z, an4.w};
    float aev[4] = {ae4.x, ae4.y, ae4.z, ae4.w};
    float ujv[4] = {uj4.x * Sinv, uj4.y * Sinv, uj4.z * Sinv, uj4.w * Sinv};
    #pragma unroll
    for (int k = 0; k < 4; ++k) {
      float vd  = bf2f(Vb[(size_t)(jt + k) * 1024 + jt + k]);
      float zn2 = anv[k] - 2.0f * aev[k] + en2;
      float gn2 = gS2 - 2.0f * ujv[k] + vd;
      sj[k] = (EPSA * sqrtf(zn2)) / sqrtf(gn2);
      nsj[k] = -sj[k];
    }
  }

  float best[4] = {NEGINF, NEGINF, NEGINF, NEGINF};
  int   bi[4]   = {0, 0, 0, 0};
  const unsigned short* Vcol = Vb + jt;
  #pragma unroll 5
  for (int i = 0; i < 125; ++i) {
    int c = c0 + i;
    float2 lu = LU[i];                                   // broadcast (lane-uniform)
    uint2 vv = *(const uint2*)(Vcol + (size_t)c * 1024); // V[c][jt..jt+3], coalesced
    float v0 = __uint_as_float(vv.x << 16);
    float v1 = __uint_as_float(vv.x & 0xffff0000u);
    float v2 = __uint_as_float(vv.y << 16);
    float v3 = __uint_as_float(vv.y & 0xffff0000u);
    float t0 = fmaf(sj[0], lu.y, lu.x);
    float t1 = fmaf(sj[1], lu.y, lu.x);
    float t2 = fmaf(sj[2], lu.y, lu.x);
    float t3 = fmaf(sj[3], lu.y, lu.x);
    float val0 = fmaf(nsj[0], v0, t0);
    float val1 = fmaf(nsj[1], v1, t1);
    float val2 = fmaf(nsj[2], v2, t2);
    float val3 = fmaf(nsj[3], v3, t3);
    if (val0 > best[0]) { best[0] = val0; bi[0] = c; }   // ascending c + strict > = first max
    if (val1 > best[1]) { best[1] = val1; bi[1] = c; }
    if (val2 > best[2]) { best[2] = val2; bi[2] = c; }
    if (val3 > best[3]) { best[3] = val3; bi[3] = c; }
  }

  if (tid < 250) {
    unsigned long long* dst = part + ((size_t)(b * 1000 + jt)) * 8 + cz;
    #pragma unroll
    for (int k = 0; k < 4; ++k) {
      unsigned ub = __float_as_uint(best[k]);
      ub = (ub & 0x80000000u) ? ~ub : (ub | 0x80000000u);
      dst[(size_t)k * 8] = ((unsigned long long)ub << 32) |
                           (unsigned long long)(0xFFFFFFFFu - (unsigned)bi[k]);  // tie -> smaller c
    }
  }
}

// ---------------------------------------------------------------- counts: merge 8 contiguous slices + pred + all(counts < 3)
__global__ __launch_bounds__(256) void counts_kernel(const unsigned long long* __restrict__ part,
                                                     const unsigned long long* __restrict__ amaxP,
                                                     float* __restrict__ out) {
  int b = blockIdx.x, t = threadIdx.x;
  __shared__ int cnt[CC];
  __shared__ int bad;
  for (int c = t; c < CC; c += 256) cnt[c] = 0;
  if (t == 0) bad = 0;
  __syncthreads();
  if (t == 0) {
    int predc = (int)(0xFFFFFFFFu - (unsigned)(amaxP[b] & 0xFFFFFFFFull));
    atomicAdd(&cnt[predc], 1);
  }
  for (int j = t; j < CC; j += 256) {
    const unsigned long long* q = part + ((size_t)(b * 1000 + j)) * 8;   // contiguous 64B
    unsigned long long key = q[0];
    #pragma unroll
    for (int cz = 1; cz < 8; ++cz) {
      unsigned long long k2 = q[cz];
      key = (k2 > key) ? k2 : key;
    }
    int c = (int)(0xFFFFFFFFu - (unsigned)(key & 0xFFFFFFFFull));
    atomicAdd(&cnt[c], 1);
  }
  __syncthreads();
  for (int c = t; c < CC; c += 256) if (cnt[c] >= NSIM) bad = 1;
  __syncthreads();
  if (t == 0) out[b] = bad ? 0.0f : 1.0f;
}

// ---------------------------------------------------------------- launch
extern "C" void kernel_launch(void* const* d_in, const int* in_sizes, int n_in,
                              void* d_out, int out_size, void* d_ws, size_t ws_size,
                              hipStream_t stream) {
  const float* x       = (const float*)d_in[0];
  const float* W_emb   = (const float*)d_in[1];
  const float* b_emb   = (const float*)d_in[2];
  const float* W_fc    = (const float*)d_in[3];
  const float* b_fc    = (const float*)d_in[4];
  const float* anchors = (const float*)d_in[5];
  float* out = (float*)d_out;

  // workspace carve (~14 MB), all aligned
  float* emb    = (float*)d_ws;               // 64*768
  float* logits = emb + BB * DD;              // 64*1000
  float* ue     = logits + BB * CC;           // 64*1000
  float* AE     = ue + BB * CC;               // 64*1000
  float* An2    = AE + BB * CC;               // 1024
  unsigned long long* amaxP = (unsigned long long*)(An2 + 1024);   // 64 u64
  unsigned long long* part  = amaxP + 64;     // 64000*8 u64 (4.1 MB), j-major
  short* Bp     = (short*)(part + 64000 * 8); // 786432 shorts
  short* Ap     = Bp + 64 * 24 * 64 * 8;      // 786432
  short* Ip     = Ap + 64 * 24 * 64 * 8;      // 786432
  short* Xp     = Ip + 48 * 32 * 64 * 8;      // 65536
  short* Ep     = Xp + 4 * 32 * 64 * 8;       // 49152
  short* Pe     = Ep + 4 * 24 * 64 * 8;       // 65536
  unsigned short* Vb = (unsigned short*)(Pe + 4 * 32 * 64 * 8);    // 1024*1024
  short* Vp     = (short*)(Vb + 1024 * 1024); // 1048576

  hipLaunchKernelGGL(prep_kernel,    dim3(1435), dim3(256), 0, stream,
                     W_fc, anchors, W_emb, x, Bp, Ap, Ip, Xp, An2, amaxP, Pe);
  hipLaunchKernelGGL(embV_kernel,    dim3(268), dim3(256), 0, stream,
                     Bp, Ip, Xp, b_emb, Vb, Vp, emb, Ep);
  hipLaunchKernelGGL(logitsAE_kernel,dim3(64, 4), dim3(64), 0, stream,
                     Ep, Bp, Ap, b_fc, logits, AE, Pe, amaxP);
  hipLaunchKernelGGL(u_kernel,       dim3(64, 4), dim3(64), 0, stream, Pe, Vp, ue);
  hipLaunchKernelGGL(scan_kernel,    dim3(BB, 8), dim3(256), 0, stream,
                     logits, ue, emb, AE, An2, Vb, part);
  hipLaunchKernelGGL(counts_kernel,  dim3(BB), dim3(256), 0, stream, part, amaxP, out);
}